// Round 12
// baseline (10353.343 us; speedup 1.0000x reference)
//
#include <hip/hip_runtime.h>

// ---------------------------------------------------------------------------
// VQ-VAE encoder — numpy-pairwise fp32 emulation (R10 design, staging FIXED).
// Ref convs hypothesized = numpy im2col port: f32 products in k=(ci,ky,kx)
// order, summed with numpy's pairwise_sum (leaves<=128: 8 interleaved lane
// accumulators r[j]=a[j], r[j]+=a[8i+j], combined ((r0+r1)+(r2+r3))+((r4+r5)
// +(r6+r7)); recursion n2=n/2 rounded down to x8). Bias added after (f32),
// relu, f32 storage. VQ = fp32 numpy-order (confirmed): t1 seq 4-term,
// t2 = seq fma chain (BLAS sgemm), d=(t1-2t2)+t3 contract(off), first-min.
// R10 bug: conv2/conv3 staged only 256 of 264 LDS entries -> garbage reads;
// this round stages all 264. Everything else identical to R10.
// d_out: z_q_st[262144] | loss[1] | idx[65536]
// ---------------------------------------------------------------------------

#define TREE8(r) ((((r)[0]+(r)[1])+((r)[2]+(r)[3]))+((((r)[4]+(r)[5]))+((r)[6]+(r)[7])))

// ---------------- conv1: 1->64, 4x4, s2, p1, 512x512 -> 256x256
// K=16, k-order (ky,kx): numpy leaf n=16: r[j]=a[j]+a[8+j], tree-combine.
__global__ __launch_bounds__(256) void conv1_kernel(
    const float* __restrict__ x, const float* __restrict__ w1,
    const float* __restrict__ b1, float* __restrict__ h1) {
#pragma clang fp contract(off)
    __shared__ __align__(16) float wl[64 * 16];
    __shared__ float bl[64];
    const int tid = threadIdx.x;
    {
        const float4* src = (const float4*)w1;
        ((float4*)wl)[tid] = src[tid];
        if (tid < 64) bl[tid] = b1[tid];
    }
    __syncthreads();

    const int oxl = tid & 63, oyq = tid >> 6;
    const int img = blockIdx.z;
    const int ox  = blockIdx.x * 64 + oxl;
    const int oy0 = blockIdx.y * 16 + oyq * 4;
    const float* xi = x + (size_t)img * 262144;

    float in[10][4];
    const int ix0 = 2 * ox - 1;
    const int iy0 = 2 * oy0 - 1;
#pragma unroll
    for (int r = 0; r < 10; ++r) {
        int iy = iy0 + r;
#pragma unroll
        for (int k = 0; k < 4; ++k) {
            int ixx = ix0 + k;
            bool ok = ((unsigned)iy < 512u) && ((unsigned)ixx < 512u);
            in[r][k] = ok ? xi[iy * 512 + ixx] : 0.f;
        }
    }

    float* outp = h1 + (size_t)img * 4194304;
#pragma unroll
    for (int c = 0; c < 64; ++c) {
        const float* wp = &wl[c * 16];
        float bv = bl[c];
#pragma unroll
        for (int p = 0; p < 4; ++p) {
            float a[16];
#pragma unroll
            for (int f = 0; f < 16; ++f)
                a[f] = in[2 * p + (f >> 2)][f & 3] * wp[f];
            float r[8];
#pragma unroll
            for (int j = 0; j < 8; ++j) r[j] = a[j] + a[8 + j];
            float tot = TREE8(r);
            outp[(size_t)c * 65536 + (size_t)(oy0 + p) * 256 + ox] =
                fmaxf(tot + bv, 0.f);
        }
    }
}

// ---------------- conv2: 64->128, 4x4, s2, p1, 256->128. K=1024.
// numpy pairwise: 8 leaves of 128 (8 ci x 16 f), lanes j over k%8.
// block: 32x * 32co; threads 256 = 16 xg (2xi) * 16 cog (2co).
__global__ __launch_bounds__(256) void conv2_kernel(
    const float* __restrict__ in, const float* __restrict__ w2,
    const float* __restrict__ bias, float* __restrict__ out) {
#pragma clang fp contract(off)
    __shared__ __align__(16) float Wl[512];      // [32co][16f] for current ci
    __shared__ __align__(16) float Il[4][68];    // 4 rows x 66 cols (+pad)
    const int tid = threadIdx.x;
    const int xg = tid & 15, cog = tid >> 4;
    const int xt = blockIdx.x & 3, cot = blockIdx.x >> 2;
    const int oy = blockIdx.y;
    const int img = blockIdx.z;
    const int xbase = 32 * xt;
    const float* inp = in + (size_t)img * 4194304;

    float r[8][2][2];   // lane accs [j][co][xi]
    float ls[8][2][2];  // leaf sums
#pragma unroll
    for (int j = 0; j < 8; ++j)
#pragma unroll
        for (int c = 0; c < 2; ++c) { r[j][c][0] = r[j][c][1] = 0.f; }

    const int gx0 = 2 * xbase - 1;
    const int iy0 = 2 * oy - 1;

    for (int L = 0; L < 8; ++L) {
        for (int cl = 0; cl < 8; ++cl) {
            int ci = 8 * L + cl;
            // stage weights [32co][16f] for this ci
            {
                int e = tid;                     // e = co*16+f
                Wl[e] = w2[(size_t)(cot * 32 + (e >> 4)) * 1024 + ci * 16 + (e & 15)];
                e = tid + 256;
                Wl[e] = w2[(size_t)(cot * 32 + (e >> 4)) * 1024 + ci * 16 + (e & 15)];
            }
            // stage input 4 rows x 66 cols for this ci  (FIXED: all 264)
            for (int e = tid; e < 264; e += 256) {
                int row = e / 66, col = e - row * 66;
                int iy = iy0 + row, gx = gx0 + col;
                bool ok = ((unsigned)iy < 256u) && ((unsigned)gx < 256u);
                Il[row][col] = ok ? inp[(size_t)ci * 65536 + iy * 256 + gx] : 0.f;
            }
            __syncthreads();

            float rin[4][6];
#pragma unroll
            for (int ky = 0; ky < 4; ++ky)
#pragma unroll
                for (int t = 0; t < 6; ++t) rin[ky][t] = Il[ky][4 * xg + t];
            float wv[2][16];
#pragma unroll
            for (int c = 0; c < 2; ++c)
#pragma unroll
                for (int f = 0; f < 16; ++f)
                    wv[c][f] = Wl[(cog * 2 + c) * 16 + f];

#pragma unroll
            for (int j = 0; j < 8; ++j) {
                int ky1 = j >> 2, kx1 = j & 3;
                int ky2 = 2 + (j >> 2), kx2 = j & 3;   // f2 = j+8
#pragma unroll
                for (int c = 0; c < 2; ++c)
#pragma unroll
                    for (int xi = 0; xi < 2; ++xi) {
                        float p1 = rin[ky1][2 * xi + kx1] * wv[c][j];
                        r[j][c][xi] = r[j][c][xi] + p1;
                        float p2 = rin[ky2][2 * xi + kx2] * wv[c][j + 8];
                        r[j][c][xi] = r[j][c][xi] + p2;
                    }
            }
            __syncthreads();
        }
        // leaf combine + reset
#pragma unroll
        for (int c = 0; c < 2; ++c)
#pragma unroll
            for (int xi = 0; xi < 2; ++xi) {
                float t01 = r[0][c][xi] + r[1][c][xi];
                float t23 = r[2][c][xi] + r[3][c][xi];
                float t45 = r[4][c][xi] + r[5][c][xi];
                float t67 = r[6][c][xi] + r[7][c][xi];
                ls[L][c][xi] = (t01 + t23) + (t45 + t67);
            }
#pragma unroll
        for (int j = 0; j < 8; ++j)
#pragma unroll
            for (int c = 0; c < 2; ++c) { r[j][c][0] = 0.f; r[j][c][1] = 0.f; }
    }

#pragma unroll
    for (int c = 0; c < 2; ++c) {
        int co = cot * 32 + cog * 2 + c;
        float bv = bias[co];
#pragma unroll
        for (int xi = 0; xi < 2; ++xi) {
            float t01 = ls[0][c][xi] + ls[1][c][xi];
            float t23 = ls[2][c][xi] + ls[3][c][xi];
            float t45 = ls[4][c][xi] + ls[5][c][xi];
            float t67 = ls[6][c][xi] + ls[7][c][xi];
            float tot = (t01 + t23) + (t45 + t67);
            int ox = xbase + 2 * xg + xi;
            out[(size_t)img * 2097152 + (size_t)co * 16384 + (size_t)oy * 128 + ox] =
                fmaxf(tot + bv, 0.f);
        }
    }
}

// ---------------- conv3: 128->128, 4x4, s2, p1, 128->64. K=2048, 16 leaves.
// block: 32x * 32co; threads 256 = 16 xg (2xi) * 16 cog (2co).
__global__ __launch_bounds__(256) void conv3_kernel(
    const float* __restrict__ in, const float* __restrict__ w3,
    const float* __restrict__ bias, float* __restrict__ out) {
#pragma clang fp contract(off)
    __shared__ __align__(16) float Wl[512];
    __shared__ __align__(16) float Il[4][68];
    const int tid = threadIdx.x;
    const int xg = tid & 15, cog = tid >> 4;
    const int xt = blockIdx.x & 1, cot = blockIdx.x >> 1;
    const int oy = blockIdx.y;
    const int img = blockIdx.z;
    const int xbase = 32 * xt;
    const float* inp = in + (size_t)img * 2097152;

    float r[8][2][2];
    float ls[16][2][2];
#pragma unroll
    for (int j = 0; j < 8; ++j)
#pragma unroll
        for (int c = 0; c < 2; ++c) { r[j][c][0] = r[j][c][1] = 0.f; }

    const int gx0 = 2 * xbase - 1;
    const int iy0 = 2 * oy - 1;

    for (int L = 0; L < 16; ++L) {
        for (int cl = 0; cl < 8; ++cl) {
            int ci = 8 * L + cl;
            {
                int e = tid;
                Wl[e] = w3[(size_t)(cot * 32 + (e >> 4)) * 2048 + ci * 16 + (e & 15)];
                e = tid + 256;
                Wl[e] = w3[(size_t)(cot * 32 + (e >> 4)) * 2048 + ci * 16 + (e & 15)];
            }
            // stage input 4 rows x 66 cols for this ci  (FIXED: all 264)
            for (int e = tid; e < 264; e += 256) {
                int row = e / 66, col = e - row * 66;
                int iy = iy0 + row, gx = gx0 + col;
                bool ok = ((unsigned)iy < 128u) && ((unsigned)gx < 128u);
                Il[row][col] = ok ? inp[(size_t)ci * 16384 + iy * 128 + gx] : 0.f;
            }
            __syncthreads();

            float rin[4][6];
#pragma unroll
            for (int ky = 0; ky < 4; ++ky)
#pragma unroll
                for (int t = 0; t < 6; ++t) rin[ky][t] = Il[ky][4 * xg + t];
            float wv[2][16];
#pragma unroll
            for (int c = 0; c < 2; ++c)
#pragma unroll
                for (int f = 0; f < 16; ++f)
                    wv[c][f] = Wl[(cog * 2 + c) * 16 + f];

#pragma unroll
            for (int j = 0; j < 8; ++j) {
                int ky1 = j >> 2, kx1 = j & 3;
                int ky2 = 2 + (j >> 2), kx2 = j & 3;
#pragma unroll
                for (int c = 0; c < 2; ++c)
#pragma unroll
                    for (int xi = 0; xi < 2; ++xi) {
                        float p1 = rin[ky1][2 * xi + kx1] * wv[c][j];
                        r[j][c][xi] = r[j][c][xi] + p1;
                        float p2 = rin[ky2][2 * xi + kx2] * wv[c][j + 8];
                        r[j][c][xi] = r[j][c][xi] + p2;
                    }
            }
            __syncthreads();
        }
#pragma unroll
        for (int c = 0; c < 2; ++c)
#pragma unroll
            for (int xi = 0; xi < 2; ++xi) {
                float t01 = r[0][c][xi] + r[1][c][xi];
                float t23 = r[2][c][xi] + r[3][c][xi];
                float t45 = r[4][c][xi] + r[5][c][xi];
                float t67 = r[6][c][xi] + r[7][c][xi];
                ls[L][c][xi] = (t01 + t23) + (t45 + t67);
            }
#pragma unroll
        for (int j = 0; j < 8; ++j)
#pragma unroll
            for (int c = 0; c < 2; ++c) { r[j][c][0] = 0.f; r[j][c][1] = 0.f; }
    }

#pragma unroll
    for (int c = 0; c < 2; ++c) {
        int co = cot * 32 + cog * 2 + c;
        float bv = bias[co];
#pragma unroll
        for (int xi = 0; xi < 2; ++xi) {
            float a01 = ls[0][c][xi] + ls[1][c][xi];
            float a23 = ls[2][c][xi] + ls[3][c][xi];
            float a45 = ls[4][c][xi] + ls[5][c][xi];
            float a67 = ls[6][c][xi] + ls[7][c][xi];
            float A = (a01 + a23) + (a45 + a67);            // p(1024) low
            float b01 = ls[8][c][xi] + ls[9][c][xi];
            float b23 = ls[10][c][xi] + ls[11][c][xi];
            float b45 = ls[12][c][xi] + ls[13][c][xi];
            float b67 = ls[14][c][xi] + ls[15][c][xi];
            float B = (b01 + b23) + (b45 + b67);            // p(1024) high
            float tot = A + B;                               // p(2048)
            int ox = xbase + 2 * xg + xi;
            out[(size_t)img * 524288 + (size_t)co * 4096 + (size_t)oy * 64 + ox] =
                fmaxf(tot + bv, 0.f);
        }
    }
}

// ---------------- conv4: 128->4, 3x3, s1, p1, 64x64 (no relu). K=1152.
// numpy pairwise: 1152->576->288->144->72: 16 leaves of 72 (8 ci x 9 f).
// threads 256 = 64 w * 4 co; one output each; blockIdx = (h, img).
__global__ __launch_bounds__(256) void conv4_kernel(
    const float* __restrict__ h3, const float* __restrict__ w4,
    const float* __restrict__ b4, float* __restrict__ z, int b0) {
#pragma clang fp contract(off)
    __shared__ __align__(16) float Il3[8][3][66];  // [cil][ky][col]
    __shared__ __align__(16) float w4l[4608];
    const int tid = threadIdx.x;
    const int wl = tid & 63, co = tid >> 6;
    const int h = blockIdx.x, bl = blockIdx.y;
    const float* inp = h3 + (size_t)bl * 524288;

    for (int it = 0; it < 18; ++it) {
        int e = tid + it * 256;
        if (e < 4608) w4l[e] = w4[e];              // raw [co][ci][ky][kx]
    }

    float ls[16];
    for (int L = 0; L < 16; ++L) {
        __syncthreads();
        // stage 8 ci x 3 rows x 66 cols (1584 entries, 7 passes)
        for (int it = 0; it < 7; ++it) {
            int e = tid + it * 256;
            if (e < 1584) {
                int cil = e / 198;
                int rem = e - cil * 198;
                int ky = rem / 66, col = rem - ky * 66;
                int iy = h - 1 + ky, gx = col - 1;
                bool ok = ((unsigned)iy < 64u) && ((unsigned)gx < 64u);
                Il3[cil][ky][col] =
                    ok ? inp[(size_t)(8 * L + cil) * 4096 + iy * 64 + gx] : 0.f;
            }
        }
        __syncthreads();

        float r[8];
#pragma unroll
        for (int j = 0; j < 8; ++j) r[j] = 0.f;
#pragma unroll
        for (int i = 0; i < 9; ++i) {
#pragma unroll
            for (int j = 0; j < 8; ++j) {
                int kk = 8 * i + j;                // 0..71, compile-time
                int cil = kk / 9, f = kk - 9 * cil;
                int ky = f / 3, kx = f - 3 * ky;
                float p = Il3[cil][ky][wl + kx] *
                          w4l[co * 1152 + (8 * L + cil) * 9 + f];
                r[j] = r[j] + p;
            }
        }
        float t01 = r[0] + r[1], t23 = r[2] + r[3];
        float t45 = r[4] + r[5], t67 = r[6] + r[7];
        ls[L] = (t01 + t23) + (t45 + t67);
    }

    // p(1152)=p(576)+p(576); 576=288+288; 288=144+144; 144=72+72
    float a01 = ls[0] + ls[1],  a23 = ls[2] + ls[3];
    float a45 = ls[4] + ls[5],  a67 = ls[6] + ls[7];
    float A = (a01 + a23) + (a45 + a67);
    float c01 = ls[8] + ls[9],  c23 = ls[10] + ls[11];
    float c45 = ls[12] + ls[13], c67 = ls[14] + ls[15];
    float B = (c01 + c23) + (c45 + c67);
    float tot = A + B;

    z[(size_t)(b0 + bl) * 16384 + (size_t)co * 4096 + (size_t)h * 64 + wl] =
        tot + b4[co];
}

// ---------------- VQ: fp32 numpy-order (confirmed). Rows = NCHW-direct.
__global__ __launch_bounds__(256) void vq_kernel(
    const float* __restrict__ z, const float* __restrict__ emb,
    float* __restrict__ zq_out, float* __restrict__ idx_out,
    float* __restrict__ loss_out) {
#pragma clang fp contract(off)
    __shared__ float4 el[512];
    __shared__ float t3s[512];
    const int tid = threadIdx.x;
#pragma unroll
    for (int i = 0; i < 2; ++i) {
        int e = tid + i * 256;
        float4 v = ((const float4*)emb)[e];
        el[e] = v;
        float q0 = v.x * v.x, q1 = v.y * v.y, q2 = v.z * v.z, q3 = v.w * v.w;
        t3s[e] = ((q0 + q1) + q2) + q3;
    }
    __syncthreads();

    const int r = blockIdx.x * 256 + tid;
    float4 v = ((const float4*)z)[r];
    float q0 = v.x * v.x, q1 = v.y * v.y, q2 = v.z * v.z, q3 = v.w * v.w;
    float t1 = ((q0 + q1) + q2) + q3;

    float best = __builtin_inff();
    int bi = 0;
    for (int jj = 0; jj < 512; ++jj) {
        float4 e = el[jj];
        float t2 = fmaf(v.x, e.x, 0.f);
        t2 = fmaf(v.y, e.y, t2);
        t2 = fmaf(v.z, e.z, t2);
        t2 = fmaf(v.w, e.w, t2);
        float two_t2 = 2.f * t2;
        float d = (t1 - two_t2) + t3s[jj];
        if (d < best) { best = d; bi = jj; }
    }
    float4 q = el[bi];
    ((float4*)zq_out)[r] = q;
    idx_out[r] = (float)bi;

    double dx = (double)q.x - v.x, dy = (double)q.y - v.y;
    double dz2 = (double)q.z - v.z, dw = (double)q.w - v.w;
    double part = dx * dx + dy * dy + dz2 * dz2 + dw * dw;
#pragma unroll
    for (int off = 32; off > 0; off >>= 1) part += __shfl_down(part, off, 64);
    __shared__ double ps[4];
    if ((tid & 63) == 0) ps[tid >> 6] = part;
    __syncthreads();
    if (tid == 0) {
        double s = ps[0] + ps[1] + ps[2] + ps[3];
        atomicAdd(loss_out, (float)(s * (1.25 / 262144.0)));
    }
}

// ---------------------------------------------------------------------------
extern "C" void kernel_launch(void* const* d_in, const int* in_sizes, int n_in,
                              void* d_out, int out_size, void* d_ws, size_t ws_size,
                              hipStream_t stream) {
    const float* x   = (const float*)d_in[0];
    const float* w1  = (const float*)d_in[1];
    const float* b1  = (const float*)d_in[2];
    const float* w2  = (const float*)d_in[3];
    const float* b2  = (const float*)d_in[4];
    const float* w3  = (const float*)d_in[5];
    const float* b3  = (const float*)d_in[6];
    const float* w4  = (const float*)d_in[7];
    const float* b4  = (const float*)d_in[8];
    const float* emb = (const float*)d_in[9];
    float* out = (float*)d_out;

    float* ws = (float*)d_ws;
    // layout (floats): zb[262144] | h1c[CH*4194304] | h2c[CH*2097152] | h3c[CH*524288]
    int CH = 4;
    while (CH > 1 &&
           ((size_t)262144u + (size_t)CH * 6815744u) * 4ull > ws_size)
        CH >>= 1;
    float* zb  = ws;
    float* h1c = ws + 262144;
    float* h2c = h1c + (size_t)CH * 4194304;
    float* h3c = h2c + (size_t)CH * 2097152;

    for (int b0 = 0; b0 < 16; b0 += CH) {
        conv1_kernel<<<dim3(4, 16, CH), 256, 0, stream>>>(
            x + (size_t)b0 * 262144, w1, b1, h1c);
        conv2_kernel<<<dim3(16, 128, CH), 256, 0, stream>>>(h1c, w2, b2, h2c);
        conv3_kernel<<<dim3(8, 64, CH), 256, 0, stream>>>(h2c, w3, b3, h3c);
        conv4_kernel<<<dim3(64, CH), 256, 0, stream>>>(h3c, w4, b4, zb, b0);
    }

    hipMemsetAsync(out + 262144, 0, sizeof(float), stream);  // loss accumulator
    vq_kernel<<<256, 256, 0, stream>>>(zb, emb, out, out + 262145, out + 262144);
}

// Round 13
// 6100.299 us; speedup vs baseline: 1.6972x; 1.6972x over previous
//
#include <hip/hip_runtime.h>

// ---------------------------------------------------------------------------
// VQ-VAE encoder — numpy-pairwise fp32 emulation (R12 semantics, PASSING).
// R13: performance restructure of conv2/conv3 ONLY. Bit-exactness invariant:
// identical products, identical per-accumulator op order, identical tree.
// Changes: per-leaf staging (8 ci/barrier-pair, 16 barriers vs 128),
// pre-transposed weights wT[ci][f][co] staged conflict-free as [cl][f][co32],
// vectorized LDS reads. conv1/conv4/vq unchanged from R12.
// d_out: z_q_st[262144] | loss[1] | idx[65536]
// ---------------------------------------------------------------------------

#define TREE8(r) ((((r)[0]+(r)[1])+((r)[2]+(r)[3]))+((((r)[4]+(r)[5]))+((r)[6]+(r)[7])))

// ---------------- weight transform: wT[ci][f][co] from w[co][ci][f]
__global__ __launch_bounds__(256) void wt_kernel(
    const float* __restrict__ w2, const float* __restrict__ w3,
    float* __restrict__ wT2, float* __restrict__ wT3) {
    int g = blockIdx.x * 256 + threadIdx.x;
    if (g < 131072) {             // conv2: ci 64, f 16, co 128
        int co = g & 127, f = (g >> 7) & 15, ci = g >> 11;
        wT2[g] = w2[co * 1024 + ci * 16 + f];
    }
    int g2 = g - 131072;
    if (g2 >= 0 && g2 < 262144) { // conv3: ci 128, f 16, co 128
        int co = g2 & 127, f = (g2 >> 7) & 15, ci = g2 >> 11;
        wT3[g2] = w3[co * 2048 + ci * 16 + f];
    }
}

// ---------------- conv1: 1->64, 4x4, s2, p1 (unchanged from R12)
__global__ __launch_bounds__(256) void conv1_kernel(
    const float* __restrict__ x, const float* __restrict__ w1,
    const float* __restrict__ b1, float* __restrict__ h1) {
#pragma clang fp contract(off)
    __shared__ __align__(16) float wl[64 * 16];
    __shared__ float bl[64];
    const int tid = threadIdx.x;
    {
        const float4* src = (const float4*)w1;
        ((float4*)wl)[tid] = src[tid];
        if (tid < 64) bl[tid] = b1[tid];
    }
    __syncthreads();

    const int oxl = tid & 63, oyq = tid >> 6;
    const int img = blockIdx.z;
    const int ox  = blockIdx.x * 64 + oxl;
    const int oy0 = blockIdx.y * 16 + oyq * 4;
    const float* xi = x + (size_t)img * 262144;

    float in[10][4];
    const int ix0 = 2 * ox - 1;
    const int iy0 = 2 * oy0 - 1;
#pragma unroll
    for (int r = 0; r < 10; ++r) {
        int iy = iy0 + r;
#pragma unroll
        for (int k = 0; k < 4; ++k) {
            int ixx = ix0 + k;
            bool ok = ((unsigned)iy < 512u) && ((unsigned)ixx < 512u);
            in[r][k] = ok ? xi[iy * 512 + ixx] : 0.f;
        }
    }

    float* outp = h1 + (size_t)img * 4194304;
#pragma unroll
    for (int c = 0; c < 64; ++c) {
        const float* wp = &wl[c * 16];
        float bv = bl[c];
#pragma unroll
        for (int p = 0; p < 4; ++p) {
            float a[16];
#pragma unroll
            for (int f = 0; f < 16; ++f)
                a[f] = in[2 * p + (f >> 2)][f & 3] * wp[f];
            float r[8];
#pragma unroll
            for (int j = 0; j < 8; ++j) r[j] = a[j] + a[8 + j];
            float tot = TREE8(r);
            outp[(size_t)c * 65536 + (size_t)(oy0 + p) * 256 + ox] =
                fmaxf(tot + bv, 0.f);
        }
    }
}

// ---------------- conv2: 64->128, 4x4, s2, p1, 256->128. K=1024, 8 leaves.
// tile 32ox x 32co x 1oy; per-leaf staging; conflict-free weight layout.
__global__ __launch_bounds__(256) void conv2_kernel(
    const float* __restrict__ in, const float* __restrict__ wT,
    const float* __restrict__ bias, float* __restrict__ out) {
#pragma clang fp contract(off)
    __shared__ __align__(16) float Wl[8][16][32];  // [cl][f][co]
    __shared__ __align__(16) float Il[8][4][68];   // [cl][row][col<=66]
    const int tid = threadIdx.x;
    const int xg = tid & 15, cog = tid >> 4;
    const int xt = blockIdx.x & 3, cot = blockIdx.x >> 2;
    const int oy = blockIdx.y;
    const int img = blockIdx.z;
    const int xbase = 32 * xt;
    const float* inp = in + (size_t)img * 4194304;
    const int gx0 = 2 * xbase - 1;
    const int iy0 = 2 * oy - 1;

    float r[8][2][2];
    float ls[8][2][2];
#pragma unroll
    for (int j = 0; j < 8; ++j)
#pragma unroll
        for (int c = 0; c < 2; ++c) { r[j][c][0] = r[j][c][1] = 0.f; }

    for (int L = 0; L < 8; ++L) {
        // stage weights for 8 ci: [cl][f][co32]
#pragma unroll
        for (int it = 0; it < 16; ++it) {
            int e = tid + it * 256;
            int co = e & 31, f = (e >> 5) & 15, cl = e >> 9;
            Wl[cl][f][co] =
                wT[(size_t)(8 * L + cl) * 2048 + f * 128 + cot * 32 + co];
        }
        // stage inputs for 8 ci: 8 x 4 x 66
        for (int e = tid; e < 2112; e += 256) {
            int cl = e / 264;
            int rem = e - cl * 264;
            int row = rem / 66, col = rem - row * 66;
            int iy = iy0 + row, gx = gx0 + col;
            bool ok = ((unsigned)iy < 256u) && ((unsigned)gx < 256u);
            Il[cl][row][col] =
                ok ? inp[(size_t)(8 * L + cl) * 65536 + iy * 256 + gx] : 0.f;
        }
        __syncthreads();

        for (int cl = 0; cl < 8; ++cl) {
            float rin[4][6];
#pragma unroll
            for (int ky = 0; ky < 4; ++ky) {
                float4 v4 = *(const float4*)&Il[cl][ky][4 * xg];
                float2 v2 = *(const float2*)&Il[cl][ky][4 * xg + 4];
                rin[ky][0] = v4.x; rin[ky][1] = v4.y; rin[ky][2] = v4.z;
                rin[ky][3] = v4.w; rin[ky][4] = v2.x; rin[ky][5] = v2.y;
            }
            float wv[2][16];
#pragma unroll
            for (int f = 0; f < 16; ++f) {
                float2 wp = *(const float2*)&Wl[cl][f][cog * 2];
                wv[0][f] = wp.x; wv[1][f] = wp.y;
            }
#pragma unroll
            for (int j = 0; j < 8; ++j) {
                int ky1 = j >> 2, kx1 = j & 3;
                int ky2 = 2 + ky1, kx2 = kx1;
#pragma unroll
                for (int c = 0; c < 2; ++c)
#pragma unroll
                    for (int xi = 0; xi < 2; ++xi) {
                        float p1 = rin[ky1][2 * xi + kx1] * wv[c][j];
                        r[j][c][xi] = r[j][c][xi] + p1;
                        float p2 = rin[ky2][2 * xi + kx2] * wv[c][j + 8];
                        r[j][c][xi] = r[j][c][xi] + p2;
                    }
            }
        }
        __syncthreads();

        // leaf combine + reset (identical tree to R12)
#pragma unroll
        for (int c = 0; c < 2; ++c)
#pragma unroll
            for (int xi = 0; xi < 2; ++xi) {
                float t01 = r[0][c][xi] + r[1][c][xi];
                float t23 = r[2][c][xi] + r[3][c][xi];
                float t45 = r[4][c][xi] + r[5][c][xi];
                float t67 = r[6][c][xi] + r[7][c][xi];
                ls[L][c][xi] = (t01 + t23) + (t45 + t67);
            }
#pragma unroll
        for (int j = 0; j < 8; ++j)
#pragma unroll
            for (int c = 0; c < 2; ++c) { r[j][c][0] = 0.f; r[j][c][1] = 0.f; }
    }

#pragma unroll
    for (int c = 0; c < 2; ++c) {
        int co = cot * 32 + cog * 2 + c;
        float bv = bias[co];
        float res[2];
#pragma unroll
        for (int xi = 0; xi < 2; ++xi) {
            float t01 = ls[0][c][xi] + ls[1][c][xi];
            float t23 = ls[2][c][xi] + ls[3][c][xi];
            float t45 = ls[4][c][xi] + ls[5][c][xi];
            float t67 = ls[6][c][xi] + ls[7][c][xi];
            float tot = (t01 + t23) + (t45 + t67);
            res[xi] = fmaxf(tot + bv, 0.f);
        }
        float2 v; v.x = res[0]; v.y = res[1];
        *(float2*)&out[(size_t)img * 2097152 + (size_t)co * 16384 +
                       (size_t)oy * 128 + xbase + 2 * xg] = v;
    }
}

// ---------------- conv3: 128->128, 4x4, s2, p1, 128->64. K=2048, 16 leaves
// as two 8-leaf halves (A+B). Same restructure as conv2.
__global__ __launch_bounds__(256) void conv3_kernel(
    const float* __restrict__ in, const float* __restrict__ wT,
    const float* __restrict__ bias, float* __restrict__ out) {
#pragma clang fp contract(off)
    __shared__ __align__(16) float Wl[8][16][32];
    __shared__ __align__(16) float Il[8][4][68];
    const int tid = threadIdx.x;
    const int xg = tid & 15, cog = tid >> 4;
    const int xt = blockIdx.x & 1, cot = blockIdx.x >> 1;
    const int oy = blockIdx.y;
    const int img = blockIdx.z;
    const int xbase = 32 * xt;
    const float* inp = in + (size_t)img * 2097152;
    const int gx0 = 2 * xbase - 1;
    const int iy0 = 2 * oy - 1;

    float r[8][2][2];
    float ls[8][2][2];
    float AB[2][2][2];
#pragma unroll
    for (int j = 0; j < 8; ++j)
#pragma unroll
        for (int c = 0; c < 2; ++c) { r[j][c][0] = r[j][c][1] = 0.f; }

    for (int half = 0; half < 2; ++half) {
        for (int L8 = 0; L8 < 8; ++L8) {
            int L = half * 8 + L8;
#pragma unroll
            for (int it = 0; it < 16; ++it) {
                int e = tid + it * 256;
                int co = e & 31, f = (e >> 5) & 15, cl = e >> 9;
                Wl[cl][f][co] =
                    wT[(size_t)(8 * L + cl) * 2048 + f * 128 + cot * 32 + co];
            }
            for (int e = tid; e < 2112; e += 256) {
                int cl = e / 264;
                int rem = e - cl * 264;
                int row = rem / 66, col = rem - row * 66;
                int iy = iy0 + row, gx = gx0 + col;
                bool ok = ((unsigned)iy < 128u) && ((unsigned)gx < 128u);
                Il[cl][row][col] =
                    ok ? inp[(size_t)(8 * L + cl) * 16384 + iy * 128 + gx] : 0.f;
            }
            __syncthreads();

            for (int cl = 0; cl < 8; ++cl) {
                float rin[4][6];
#pragma unroll
                for (int ky = 0; ky < 4; ++ky) {
                    float4 v4 = *(const float4*)&Il[cl][ky][4 * xg];
                    float2 v2 = *(const float2*)&Il[cl][ky][4 * xg + 4];
                    rin[ky][0] = v4.x; rin[ky][1] = v4.y; rin[ky][2] = v4.z;
                    rin[ky][3] = v4.w; rin[ky][4] = v2.x; rin[ky][5] = v2.y;
                }
                float wv[2][16];
#pragma unroll
                for (int f = 0; f < 16; ++f) {
                    float2 wp = *(const float2*)&Wl[cl][f][cog * 2];
                    wv[0][f] = wp.x; wv[1][f] = wp.y;
                }
#pragma unroll
                for (int j = 0; j < 8; ++j) {
                    int ky1 = j >> 2, kx1 = j & 3;
                    int ky2 = 2 + ky1, kx2 = kx1;
#pragma unroll
                    for (int c = 0; c < 2; ++c)
#pragma unroll
                        for (int xi = 0; xi < 2; ++xi) {
                            float p1 = rin[ky1][2 * xi + kx1] * wv[c][j];
                            r[j][c][xi] = r[j][c][xi] + p1;
                            float p2 = rin[ky2][2 * xi + kx2] * wv[c][j + 8];
                            r[j][c][xi] = r[j][c][xi] + p2;
                        }
                }
            }
            __syncthreads();

#pragma unroll
            for (int c = 0; c < 2; ++c)
#pragma unroll
                for (int xi = 0; xi < 2; ++xi) {
                    float t01 = r[0][c][xi] + r[1][c][xi];
                    float t23 = r[2][c][xi] + r[3][c][xi];
                    float t45 = r[4][c][xi] + r[5][c][xi];
                    float t67 = r[6][c][xi] + r[7][c][xi];
                    ls[L8][c][xi] = (t01 + t23) + (t45 + t67);
                }
#pragma unroll
            for (int j = 0; j < 8; ++j)
#pragma unroll
                for (int c = 0; c < 2; ++c) { r[j][c][0] = 0.f; r[j][c][1] = 0.f; }
        }
        // half combine: p(1024) over these 8 leaves
#pragma unroll
        for (int c = 0; c < 2; ++c)
#pragma unroll
            for (int xi = 0; xi < 2; ++xi) {
                float t01 = ls[0][c][xi] + ls[1][c][xi];
                float t23 = ls[2][c][xi] + ls[3][c][xi];
                float t45 = ls[4][c][xi] + ls[5][c][xi];
                float t67 = ls[6][c][xi] + ls[7][c][xi];
                AB[half][c][xi] = (t01 + t23) + (t45 + t67);
            }
    }

#pragma unroll
    for (int c = 0; c < 2; ++c) {
        int co = cot * 32 + cog * 2 + c;
        float bv = bias[co];
        float res[2];
#pragma unroll
        for (int xi = 0; xi < 2; ++xi) {
            float tot = AB[0][c][xi] + AB[1][c][xi];   // p(2048)
            res[xi] = fmaxf(tot + bv, 0.f);
        }
        float2 v; v.x = res[0]; v.y = res[1];
        *(float2*)&out[(size_t)img * 524288 + (size_t)co * 4096 +
                       (size_t)oy * 64 + xbase + 2 * xg] = v;
    }
}

// ---------------- conv4: 128->4, 3x3, s1, p1 (unchanged from R12)
__global__ __launch_bounds__(256) void conv4_kernel(
    const float* __restrict__ h3, const float* __restrict__ w4,
    const float* __restrict__ b4, float* __restrict__ z, int b0) {
#pragma clang fp contract(off)
    __shared__ __align__(16) float Il3[8][3][66];
    __shared__ __align__(16) float w4l[4608];
    const int tid = threadIdx.x;
    const int wl = tid & 63, co = tid >> 6;
    const int h = blockIdx.x, bl = blockIdx.y;
    const float* inp = h3 + (size_t)bl * 524288;

    for (int it = 0; it < 18; ++it) {
        int e = tid + it * 256;
        if (e < 4608) w4l[e] = w4[e];
    }

    float ls[16];
    for (int L = 0; L < 16; ++L) {
        __syncthreads();
        for (int it = 0; it < 7; ++it) {
            int e = tid + it * 256;
            if (e < 1584) {
                int cil = e / 198;
                int rem = e - cil * 198;
                int ky = rem / 66, col = rem - ky * 66;
                int iy = h - 1 + ky, gx = col - 1;
                bool ok = ((unsigned)iy < 64u) && ((unsigned)gx < 64u);
                Il3[cil][ky][col] =
                    ok ? inp[(size_t)(8 * L + cil) * 4096 + iy * 64 + gx] : 0.f;
            }
        }
        __syncthreads();

        float r[8];
#pragma unroll
        for (int j = 0; j < 8; ++j) r[j] = 0.f;
#pragma unroll
        for (int i = 0; i < 9; ++i) {
#pragma unroll
            for (int j = 0; j < 8; ++j) {
                int kk = 8 * i + j;
                int cil = kk / 9, f = kk - 9 * cil;
                int ky = f / 3, kx = f - 3 * ky;
                float p = Il3[cil][ky][wl + kx] *
                          w4l[co * 1152 + (8 * L + cil) * 9 + f];
                r[j] = r[j] + p;
            }
        }
        float t01 = r[0] + r[1], t23 = r[2] + r[3];
        float t45 = r[4] + r[5], t67 = r[6] + r[7];
        ls[L] = (t01 + t23) + (t45 + t67);
    }

    float a01 = ls[0] + ls[1],  a23 = ls[2] + ls[3];
    float a45 = ls[4] + ls[5],  a67 = ls[6] + ls[7];
    float A = (a01 + a23) + (a45 + a67);
    float c01 = ls[8] + ls[9],  c23 = ls[10] + ls[11];
    float c45 = ls[12] + ls[13], c67 = ls[14] + ls[15];
    float B = (c01 + c23) + (c45 + c67);
    float tot = A + B;

    z[(size_t)(b0 + bl) * 16384 + (size_t)co * 4096 + (size_t)h * 64 + wl] =
        tot + b4[co];
}

// ---------------- VQ (unchanged from R12)
__global__ __launch_bounds__(256) void vq_kernel(
    const float* __restrict__ z, const float* __restrict__ emb,
    float* __restrict__ zq_out, float* __restrict__ idx_out,
    float* __restrict__ loss_out) {
#pragma clang fp contract(off)
    __shared__ float4 el[512];
    __shared__ float t3s[512];
    const int tid = threadIdx.x;
#pragma unroll
    for (int i = 0; i < 2; ++i) {
        int e = tid + i * 256;
        float4 v = ((const float4*)emb)[e];
        el[e] = v;
        float q0 = v.x * v.x, q1 = v.y * v.y, q2 = v.z * v.z, q3 = v.w * v.w;
        t3s[e] = ((q0 + q1) + q2) + q3;
    }
    __syncthreads();

    const int r = blockIdx.x * 256 + tid;
    float4 v = ((const float4*)z)[r];
    float q0 = v.x * v.x, q1 = v.y * v.y, q2 = v.z * v.z, q3 = v.w * v.w;
    float t1 = ((q0 + q1) + q2) + q3;

    float best = __builtin_inff();
    int bi = 0;
    for (int jj = 0; jj < 512; ++jj) {
        float4 e = el[jj];
        float t2 = fmaf(v.x, e.x, 0.f);
        t2 = fmaf(v.y, e.y, t2);
        t2 = fmaf(v.z, e.z, t2);
        t2 = fmaf(v.w, e.w, t2);
        float two_t2 = 2.f * t2;
        float d = (t1 - two_t2) + t3s[jj];
        if (d < best) { best = d; bi = jj; }
    }
    float4 q = el[bi];
    ((float4*)zq_out)[r] = q;
    idx_out[r] = (float)bi;

    double dx = (double)q.x - v.x, dy = (double)q.y - v.y;
    double dz2 = (double)q.z - v.z, dw = (double)q.w - v.w;
    double part = dx * dx + dy * dy + dz2 * dz2 + dw * dw;
#pragma unroll
    for (int off = 32; off > 0; off >>= 1) part += __shfl_down(part, off, 64);
    __shared__ double ps[4];
    if ((tid & 63) == 0) ps[tid >> 6] = part;
    __syncthreads();
    if (tid == 0) {
        double s = ps[0] + ps[1] + ps[2] + ps[3];
        atomicAdd(loss_out, (float)(s * (1.25 / 262144.0)));
    }
}

// ---------------------------------------------------------------------------
extern "C" void kernel_launch(void* const* d_in, const int* in_sizes, int n_in,
                              void* d_out, int out_size, void* d_ws, size_t ws_size,
                              hipStream_t stream) {
    const float* x   = (const float*)d_in[0];
    const float* w1  = (const float*)d_in[1];
    const float* b1  = (const float*)d_in[2];
    const float* w2  = (const float*)d_in[3];
    const float* b2  = (const float*)d_in[4];
    const float* w3  = (const float*)d_in[5];
    const float* b3  = (const float*)d_in[6];
    const float* w4  = (const float*)d_in[7];
    const float* b4  = (const float*)d_in[8];
    const float* emb = (const float*)d_in[9];
    float* out = (float*)d_out;

    float* ws = (float*)d_ws;
    // layout (floats): zb[262144] | wT2[131072] | wT3[262144]
    //                 | h1c[CH*4194304] | h2c[CH*2097152] | h3c[CH*524288]
    int CH = 4;
    while (CH > 1 &&
           ((size_t)655360u + (size_t)CH * 6815744u) * 4ull > ws_size)
        CH >>= 1;
    float* zb  = ws;
    float* wT2 = ws + 262144;
    float* wT3 = wT2 + 131072;
    float* h1c = wT3 + 262144;
    float* h2c = h1c + (size_t)CH * 4194304;
    float* h3c = h2c + (size_t)CH * 2097152;

    wt_kernel<<<1536, 256, 0, stream>>>(w2, w3, wT2, wT3);

    for (int b0 = 0; b0 < 16; b0 += CH) {
        conv1_kernel<<<dim3(4, 16, CH), 256, 0, stream>>>(
            x + (size_t)b0 * 262144, w1, b1, h1c);
        conv2_kernel<<<dim3(16, 128, CH), 256, 0, stream>>>(h1c, wT2, b2, h2c);
        conv3_kernel<<<dim3(8, 64, CH), 256, 0, stream>>>(h2c, wT3, b3, h3c);
        conv4_kernel<<<dim3(64, CH), 256, 0, stream>>>(h3c, w4, b4, zb, b0);
    }

    hipMemsetAsync(out + 262144, 0, sizeof(float), stream);  // loss accumulator
    vq_kernel<<<256, 256, 0, stream>>>(zb, emb, out, out + 262145, out + 262144);
}